// Round 2
// baseline (10402.760 us; speedup 1.0000x reference)
//
#include <hip/hip_runtime.h>
#include <hip/hip_bf16.h>

// GRU-D layer: B=256, T=512, D=128, H=256, fp32.
// Phase 1: xg = x @ Wg + bg  (g in {z,r,h}) -- parallel GEMM.
//          xh -> d_out (read at step t, then overwritten by h_t: safe).
//          xz, xr -> d_ws (fp32 if ws_size allows, else bf16).
// Phase 2: persistent scan kernel, 1 block per batch, 1024 threads.
//          U matrices held ENTIRELY IN REGISTERS (192 fp32/thread):
//          thread (j = tid&255, q = tid>>8) owns U[(q*64 .. q*64+64), j]
//          for all three matrices. Removes the ~100 GB L2 U-stream that
//          made R1's scan 4.05 ms.

static constexpr int Bb = 256;
static constexpr int Tt = 512;
static constexpr int Dd = 128;
static constexpr int Hh = 256;

// ---------------------------------------------------------------------------
// Phase 1: C[64-row tile, 256] = x_tile[64,128] @ W[128,256] + bias
// (unchanged from R1 -- not the bottleneck yet)
// ---------------------------------------------------------------------------
template<bool BF16OUT>
__global__ __launch_bounds__(256) void proj_kernel(
    const float* __restrict__ x, const float* __restrict__ W,
    const float* __restrict__ bias, void* __restrict__ outv)
{
  __shared__ float xT[Dd][68];
  __shared__ float wS[16][Hh];

  const int tid = threadIdx.x;
  const int ty = tid >> 5;
  const int tx = tid & 31;
  const size_t brow = (size_t)blockIdx.x * 64;
  const float* xp = x + brow * Dd;

  #pragma unroll
  for (int it = 0; it < 8; ++it) {
    int idx = it * 256 + tid;
    int row = idx & 63;
    int kq  = idx >> 6;
    float4 v = *(const float4*)(xp + row * Dd + kq * 4);
    xT[kq * 4 + 0][row] = v.x;
    xT[kq * 4 + 1][row] = v.y;
    xT[kq * 4 + 2][row] = v.z;
    xT[kq * 4 + 3][row] = v.w;
  }

  float bv[8];
  *(float4*)&bv[0] = *(const float4*)(bias + tx * 8);
  *(float4*)&bv[4] = *(const float4*)(bias + tx * 8 + 4);

  float acc[8][8];
  #pragma unroll
  for (int i = 0; i < 8; ++i)
    #pragma unroll
    for (int jj = 0; jj < 8; ++jj) acc[i][jj] = 0.f;

  for (int s = 0; s < 8; ++s) {
    #pragma unroll
    for (int it = 0; it < 4; ++it) {
      int idx = it * 256 + tid;
      int kr = idx >> 6;
      int cq = idx & 63;
      *(float4*)&wS[kr][cq * 4] =
          *(const float4*)(W + (size_t)(s * 16 + kr) * Hh + cq * 4);
    }
    __syncthreads();

    #pragma unroll
    for (int kk = 0; kk < 16; ++kk) {
      const int k = s * 16 + kk;
      float xv[8], wv[8];
      *(float4*)&xv[0] = *(const float4*)&xT[k][ty * 8];
      *(float4*)&xv[4] = *(const float4*)&xT[k][ty * 8 + 4];
      *(float4*)&wv[0] = *(const float4*)&wS[kk][tx * 8];
      *(float4*)&wv[4] = *(const float4*)&wS[kk][tx * 8 + 4];
      #pragma unroll
      for (int i = 0; i < 8; ++i)
        #pragma unroll
        for (int jj = 0; jj < 8; ++jj)
          acc[i][jj] = fmaf(xv[i], wv[jj], acc[i][jj]);
    }
    __syncthreads();
  }

  if (!BF16OUT) {
    float* of = (float*)outv;
    #pragma unroll
    for (int i = 0; i < 8; ++i) {
      size_t ro = (brow + (size_t)ty * 8 + i) * Hh + tx * 8;
      float4 a{acc[i][0] + bv[0], acc[i][1] + bv[1],
               acc[i][2] + bv[2], acc[i][3] + bv[3]};
      float4 c{acc[i][4] + bv[4], acc[i][5] + bv[5],
               acc[i][6] + bv[6], acc[i][7] + bv[7]};
      *(float4*)(of + ro) = a;
      *(float4*)(of + ro + 4) = c;
    }
  } else {
    __hip_bfloat16* ob = (__hip_bfloat16*)outv;
    #pragma unroll
    for (int i = 0; i < 8; ++i) {
      size_t ro = (brow + (size_t)ty * 8 + i) * Hh + tx * 8;
      __hip_bfloat16 tmp[8];
      #pragma unroll
      for (int jj = 0; jj < 8; ++jj)
        tmp[jj] = __float2bfloat16(acc[i][jj] + bv[jj]);
      *(uint4*)(ob + ro) = *(uint4*)tmp;
    }
  }
}

// ---------------------------------------------------------------------------
// Phase 2: persistent scan, U in registers.
// 1 block = 1 batch, 1024 threads: j = tid&255 (output col), q = tid>>8
// (k-quarter, 64 k each). 4 barriers/step:
//   P2: z/r matvec partials (all threads, U regs x LDS-broadcast h_dec)
//   P3: q==0 reduce+sigmoid -> rh_lds
//   P4: h matvec partials
//   P5: q==0 reduce+tanh+combine -> out, h_dec(t+1), prefetch x*(t+1)
// ---------------------------------------------------------------------------
template<bool PROJBF16>
__global__ __launch_bounds__(1024) void gru_scan(
    const void* __restrict__ xz_v, const void* __restrict__ xr_v,
    const float* __restrict__ hdecay,
    const float* __restrict__ Uz, const float* __restrict__ Ur,
    const float* __restrict__ Uh, float* __restrict__ out)
{
  const int b   = blockIdx.x;
  const int tid = threadIdx.x;
  const int j   = tid & (Hh - 1);
  const int q   = tid >> 8;         // 0..3, wave-uniform
  const int k0  = q << 6;           // 0,64,128,192

  // ---- U columns into registers: 3 x 64 fp32 = 192 VGPRs ----
  float uz[64], ur[64], uh[64];
  {
    const float* uzp = Uz + (size_t)k0 * Hh + j;
    const float* urp = Ur + (size_t)k0 * Hh + j;
    const float* uhp = Uh + (size_t)k0 * Hh + j;
    #pragma unroll
    for (int k = 0; k < 64; ++k) {
      uz[k] = uzp[(size_t)k * Hh];
      ur[k] = urp[(size_t)k * Hh];
      uh[k] = uhp[(size_t)k * Hh];
    }
  }

  __shared__ float hdec_lds[Hh];
  __shared__ float rh_lds[Hh];
  __shared__ float pz[4][Hh];
  __shared__ float pr[4][Hh];
  __shared__ float ph[4][Hh];

  const float* xzf = (const float*)xz_v;
  const float* xrf = (const float*)xr_v;
  const __hip_bfloat16* xzb = (const __hip_bfloat16*)xz_v;
  const __hip_bfloat16* xrb = (const __hip_bfloat16*)xr_v;

  float z = 0.f, r = 0.f, xzt = 0.f, xrt = 0.f, xht = 0.f;

  // prologue: h0 = 0 -> hdec(0) = 0; prefetch t=0 inputs
  if (q == 0) {
    hdec_lds[j] = 0.f;
    const size_t base0 = (size_t)b * Tt * Hh + j;
    if (PROJBF16) {
      xzt = __bfloat162float(xzb[base0]);
      xrt = __bfloat162float(xrb[base0]);
    } else {
      xzt = xzf[base0];
      xrt = xrf[base0];
    }
    xht = out[base0];
  }
  __syncthreads();

  for (int t = 0; t < Tt; ++t) {
    const size_t base = ((size_t)b * Tt + t) * Hh;

    // ---- P2: z/r matvec partials over own k-quarter ----
    {
      float az0 = 0.f, az1 = 0.f, ar0 = 0.f, ar1 = 0.f;
      #pragma unroll
      for (int kk = 0; kk < 64; kk += 8) {
        float4 h0 = *(const float4*)&hdec_lds[k0 + kk];
        float4 h1 = *(const float4*)&hdec_lds[k0 + kk + 4];
        az0 = fmaf(h0.x, uz[kk + 0], az0);
        az0 = fmaf(h0.y, uz[kk + 1], az0);
        az0 = fmaf(h0.z, uz[kk + 2], az0);
        az0 = fmaf(h0.w, uz[kk + 3], az0);
        az1 = fmaf(h1.x, uz[kk + 4], az1);
        az1 = fmaf(h1.y, uz[kk + 5], az1);
        az1 = fmaf(h1.z, uz[kk + 6], az1);
        az1 = fmaf(h1.w, uz[kk + 7], az1);
        ar0 = fmaf(h0.x, ur[kk + 0], ar0);
        ar0 = fmaf(h0.y, ur[kk + 1], ar0);
        ar0 = fmaf(h0.z, ur[kk + 2], ar0);
        ar0 = fmaf(h0.w, ur[kk + 3], ar0);
        ar1 = fmaf(h1.x, ur[kk + 4], ar1);
        ar1 = fmaf(h1.y, ur[kk + 5], ar1);
        ar1 = fmaf(h1.z, ur[kk + 6], ar1);
        ar1 = fmaf(h1.w, ur[kk + 7], ar1);
      }
      pz[q][j] = az0 + az1;
      pr[q][j] = ar0 + ar1;
    }
    __syncthreads();

    // ---- P3: gates (q==0 only) ----
    if (q == 0) {
      float zs = xzt + ((pz[0][j] + pz[1][j]) + (pz[2][j] + pz[3][j]));
      float rs = xrt + ((pr[0][j] + pr[1][j]) + (pr[2][j] + pr[3][j]));
      z = 1.f / (1.f + __expf(-zs));
      r = 1.f / (1.f + __expf(-rs));
      rh_lds[j] = r * hdec_lds[j];
    }
    __syncthreads();

    // ---- P4: h matvec partials ----
    {
      float ah0 = 0.f, ah1 = 0.f;
      #pragma unroll
      for (int kk = 0; kk < 64; kk += 8) {
        float4 r0 = *(const float4*)&rh_lds[k0 + kk];
        float4 r1 = *(const float4*)&rh_lds[k0 + kk + 4];
        ah0 = fmaf(r0.x, uh[kk + 0], ah0);
        ah0 = fmaf(r0.y, uh[kk + 1], ah0);
        ah0 = fmaf(r0.z, uh[kk + 2], ah0);
        ah0 = fmaf(r0.w, uh[kk + 3], ah0);
        ah1 = fmaf(r1.x, uh[kk + 4], ah1);
        ah1 = fmaf(r1.y, uh[kk + 5], ah1);
        ah1 = fmaf(r1.z, uh[kk + 6], ah1);
        ah1 = fmaf(r1.w, uh[kk + 7], ah1);
      }
      ph[q][j] = ah0 + ah1;
    }
    __syncthreads();

    // ---- P5: combine (q==0), write h_t, prep t+1 ----
    if (q == 0) {
      float hs = xht + ((ph[0][j] + ph[1][j]) + (ph[2][j] + ph[3][j]));
      float e  = __expf(-2.f * fabsf(hs));
      float m  = (1.f - e) / (1.f + e);
      float hp = copysignf(m, hs);
      float hd = hdec_lds[j];
      float hn = (1.f - z) * hd + z * hp;
      out[base + j] = hn;
      if (t + 1 < Tt) {
        float dec = hdecay[b * Tt + t + 1];
        hdec_lds[j] = dec * hn;
        const size_t nbase = base + Hh + j;
        if (PROJBF16) {
          xzt = __bfloat162float(xzb[nbase]);
          xrt = __bfloat162float(xrb[nbase]);
        } else {
          xzt = xzf[nbase];
          xrt = xrf[nbase];
        }
        xht = out[nbase];
      }
    }
    __syncthreads();
  }
}

// ---------------------------------------------------------------------------
extern "C" void kernel_launch(void* const* d_in, const int* in_sizes, int n_in,
                              void* d_out, int out_size, void* d_ws, size_t ws_size,
                              hipStream_t stream) {
  const float* x   = (const float*)d_in[0];
  const float* hdc = (const float*)d_in[1];
  const float* Wr  = (const float*)d_in[2];
  const float* Wz  = (const float*)d_in[3];
  const float* Wh  = (const float*)d_in[4];
  const float* Ur  = (const float*)d_in[5];
  const float* Uz  = (const float*)d_in[6];
  const float* Uh  = (const float*)d_in[7];
  const float* br  = (const float*)d_in[8];
  const float* bz  = (const float*)d_in[9];
  const float* bh  = (const float*)d_in[10];
  float* out = (float*)d_out;

  const size_t bth = (size_t)Bb * Tt * Hh;   // 33,554,432 elements
  dim3 pgrid(2048), pblk(256);

  // xh -> d_out (always fp32)
  proj_kernel<false><<<pgrid, pblk, 0, stream>>>(x, Wh, bh, (void*)out);

  if (ws_size >= bth * 2 * sizeof(float)) {
    float* wsz = (float*)d_ws;
    float* wsr = wsz + bth;
    proj_kernel<false><<<pgrid, pblk, 0, stream>>>(x, Wz, bz, (void*)wsz);
    proj_kernel<false><<<pgrid, pblk, 0, stream>>>(x, Wr, br, (void*)wsr);
    gru_scan<false><<<dim3(Bb), dim3(1024), 0, stream>>>(
        (const void*)wsz, (const void*)wsr, hdc, Uz, Ur, Uh, out);
  } else if (ws_size >= bth * 2 * sizeof(__hip_bfloat16)) {
    __hip_bfloat16* wsz = (__hip_bfloat16*)d_ws;
    __hip_bfloat16* wsr = wsz + bth;
    proj_kernel<true><<<pgrid, pblk, 0, stream>>>(x, Wz, bz, (void*)wsz);
    proj_kernel<true><<<pgrid, pblk, 0, stream>>>(x, Wr, br, (void*)wsr);
    gru_scan<true><<<dim3(Bb), dim3(1024), 0, stream>>>(
        (const void*)wsz, (const void*)wsr, hdc, Uz, Ur, Uh, out);
  }
}

// Round 3
// 4292.816 us; speedup vs baseline: 2.4233x; 2.4233x over previous
//
#include <hip/hip_runtime.h>
#include <hip/hip_bf16.h>

// GRU-D layer: B=256, T=512, D=128, H=256, fp32.
// Phase 1: xg = x @ Wg + bg (3x GEMM). xh -> d_out, xz/xr -> d_ws.
// Phase 2 (R3): MFMA scan. 16 blocks x 16 batches, 256 threads (4 waves).
//   U (bf16) resident in VGPRs as MFMA B-fragments: 3 mats x 4 tiles x
//   8 ksteps x 4 regs = 384 VGPRs/thread. A (h_dec, r*h_dec) staged in
//   XOR-swizzled LDS as bf16. mfma_f32_16x16x32_bf16, 96 MFMA/wave/step.
//   R2 lesson: fp32 U (768KB) > 512KB/CU regfile -> spilled (VGPR=64,
//   28.5GB scratch fetch). bf16 U (384KB) fits at 4 waves/CU.

static constexpr int Bb = 256;
static constexpr int Tt = 512;
static constexpr int Dd = 128;
static constexpr int Hh = 256;

typedef short bf16x8_t __attribute__((ext_vector_type(8)));
typedef float f32x4 __attribute__((ext_vector_type(4)));

// ---------------------------------------------------------------------------
// Phase 1 GEMM (unchanged from R1 -- correct, ~noise so far)
// ---------------------------------------------------------------------------
template<bool BF16OUT>
__global__ __launch_bounds__(256) void proj_kernel(
    const float* __restrict__ x, const float* __restrict__ W,
    const float* __restrict__ bias, void* __restrict__ outv)
{
  __shared__ float xT[Dd][68];
  __shared__ float wS[16][Hh];

  const int tid = threadIdx.x;
  const int ty = tid >> 5;
  const int tx = tid & 31;
  const size_t brow = (size_t)blockIdx.x * 64;
  const float* xp = x + brow * Dd;

  #pragma unroll
  for (int it = 0; it < 8; ++it) {
    int idx = it * 256 + tid;
    int row = idx & 63;
    int kq  = idx >> 6;
    float4 v = *(const float4*)(xp + row * Dd + kq * 4);
    xT[kq * 4 + 0][row] = v.x;
    xT[kq * 4 + 1][row] = v.y;
    xT[kq * 4 + 2][row] = v.z;
    xT[kq * 4 + 3][row] = v.w;
  }

  float bv[8];
  *(float4*)&bv[0] = *(const float4*)(bias + tx * 8);
  *(float4*)&bv[4] = *(const float4*)(bias + tx * 8 + 4);

  float acc[8][8];
  #pragma unroll
  for (int i = 0; i < 8; ++i)
    #pragma unroll
    for (int jj = 0; jj < 8; ++jj) acc[i][jj] = 0.f;

  for (int s = 0; s < 8; ++s) {
    #pragma unroll
    for (int it = 0; it < 4; ++it) {
      int idx = it * 256 + tid;
      int kr = idx >> 6;
      int cq = idx & 63;
      *(float4*)&wS[kr][cq * 4] =
          *(const float4*)(W + (size_t)(s * 16 + kr) * Hh + cq * 4);
    }
    __syncthreads();

    #pragma unroll
    for (int kk = 0; kk < 16; ++kk) {
      const int k = s * 16 + kk;
      float xv[8], wv[8];
      *(float4*)&xv[0] = *(const float4*)&xT[k][ty * 8];
      *(float4*)&xv[4] = *(const float4*)&xT[k][ty * 8 + 4];
      *(float4*)&wv[0] = *(const float4*)&wS[kk][tx * 8];
      *(float4*)&wv[4] = *(const float4*)&wS[kk][tx * 8 + 4];
      #pragma unroll
      for (int i = 0; i < 8; ++i)
        #pragma unroll
        for (int jj = 0; jj < 8; ++jj)
          acc[i][jj] = fmaf(xv[i], wv[jj], acc[i][jj]);
    }
    __syncthreads();
  }

  if (!BF16OUT) {
    float* of = (float*)outv;
    #pragma unroll
    for (int i = 0; i < 8; ++i) {
      size_t ro = (brow + (size_t)ty * 8 + i) * Hh + tx * 8;
      float4 a{acc[i][0] + bv[0], acc[i][1] + bv[1],
               acc[i][2] + bv[2], acc[i][3] + bv[3]};
      float4 c{acc[i][4] + bv[4], acc[i][5] + bv[5],
               acc[i][6] + bv[6], acc[i][7] + bv[7]};
      *(float4*)(of + ro) = a;
      *(float4*)(of + ro + 4) = c;
    }
  } else {
    __hip_bfloat16* ob = (__hip_bfloat16*)outv;
    #pragma unroll
    for (int i = 0; i < 8; ++i) {
      size_t ro = (brow + (size_t)ty * 8 + i) * Hh + tx * 8;
      __hip_bfloat16 tmp[8];
      #pragma unroll
      for (int jj = 0; jj < 8; ++jj)
        tmp[jj] = __float2bfloat16(acc[i][jj] + bv[jj]);
      *(uint4*)(ob + ro) = *(uint4*)tmp;
    }
  }
}

// ---------------------------------------------------------------------------
// Phase 2: MFMA scan
// ---------------------------------------------------------------------------
__device__ __forceinline__ unsigned short bfbits(float f) {
  __hip_bfloat16 h = __float2bfloat16(f);
  return *reinterpret_cast<unsigned short*>(&h);
}

// B fragment for mfma_f32_16x16x32_bf16: lane holds B[k][col] with
// col = c0 + (lane&15), k = 32*ks + 8*(lane>>4) + i, i=0..7.
__device__ __forceinline__ bf16x8_t load_ufrag(
    const float* __restrict__ U, int c0, int ks, int lane)
{
  const int col = c0 + (lane & 15);
  const int kb  = 32 * ks + 8 * (lane >> 4);
  bf16x8_t v;
  #pragma unroll
  for (int i = 0; i < 8; ++i)
    v[i] = (short)bfbits(U[(size_t)(kb + i) * Hh + col]);
  return v;
}

template<bool PROJBF16>
__global__ __launch_bounds__(256, 1) void gru_scan_mfma(
    const void* __restrict__ xz_v, const void* __restrict__ xr_v,
    const float* __restrict__ hdecay,
    const float* __restrict__ Uz, const float* __restrict__ Ur,
    const float* __restrict__ Uh, float* __restrict__ out)
{
  const int tid  = threadIdx.x;
  const int lane = tid & 63;
  const int w    = tid >> 6;        // wave 0..3 -> cols [64w, 64w+64)
  const int q    = lane >> 4;       // 0..3
  const int p    = lane & 15;
  const int b0   = blockIdx.x * 16; // 16 batches per block

  // A buffers: [16 rows][256 cols] bf16 = 8 KB each, XOR-swizzled
  // (byte ^= (row&7)<<4) so A-frag ds_read_b128 is conflict-free.
  __shared__ __align__(16) char Ahd[16 * 512];  // bf16(h_dec)
  __shared__ __align__(16) char Ard[16 * 512];  // bf16(r*h_dec)

  // ---- U into registers as bf16 B-fragments: 3*4*8*4 = 384 VGPRs ----
  bf16x8_t ubz[4][8], ubr[4][8], ubh[4][8];
  #pragma unroll
  for (int n = 0; n < 4; ++n) {
    const int c0 = w * 64 + n * 16;
    #pragma unroll
    for (int ks = 0; ks < 8; ++ks) {
      ubz[n][ks] = load_ufrag(Uz, c0, ks, lane);
      ubr[n][ks] = load_ufrag(Ur, c0, ks, lane);
      ubh[n][ks] = load_ufrag(Uh, c0, ks, lane);
    }
  }

  // zero Ahd (h0 = 0 -> h_dec(0) = 0)
  #pragma unroll
  for (int i = 0; i < 8; ++i)
    ((unsigned*)Ahd)[tid + 256 * i] = 0u;

  const float* xzf = (const float*)xz_v;
  const float* xrf = (const float*)xr_v;
  const __hip_bfloat16* xzb = (const __hip_bfloat16*)xz_v;
  const __hip_bfloat16* xrb = (const __hip_bfloat16*)xr_v;

  float hdec[4][4];                 // this lane's h_dec at its C-layout slots
  #pragma unroll
  for (int n = 0; n < 4; ++n)
    #pragma unroll
    for (int e = 0; e < 4; ++e) hdec[n][e] = 0.f;

  __syncthreads();

  for (int t = 0; t < Tt; ++t) {
    // row base offsets for this lane's 4 rows (batch = b0 + 4q + e)
    size_t rb[4];
    #pragma unroll
    for (int e = 0; e < 4; ++e)
      rb[e] = ((size_t)(b0 + 4 * q + e) * Tt + t) * Hh;

    // ---- issue xz/xr loads (consumed after ZR MFMAs) ----
    float xzv[4][4], xrv[4][4];
    #pragma unroll
    for (int n = 0; n < 4; ++n) {
      const int col = w * 64 + n * 16 + p;
      #pragma unroll
      for (int e = 0; e < 4; ++e) {
        if (PROJBF16) {
          xzv[n][e] = __bfloat162float(xzb[rb[e] + col]);
          xrv[n][e] = __bfloat162float(xrb[rb[e] + col]);
        } else {
          xzv[n][e] = xzf[rb[e] + col];
          xrv[n][e] = xrf[rb[e] + col];
        }
      }
    }

    // ---- phase ZR: acc = A(h_dec) @ U{z,r} ----
    f32x4 accZ[4], accR[4];
    #pragma unroll
    for (int n = 0; n < 4; ++n) { accZ[n] = (f32x4)0.f; accR[n] = (f32x4)0.f; }
    #pragma unroll
    for (int ks = 0; ks < 8; ++ks) {
      const int cb = (64 * ks + 16 * q) ^ ((p & 7) << 4);
      bf16x8_t a = *(const bf16x8_t*)(Ahd + p * 512 + cb);
      #pragma unroll
      for (int n = 0; n < 4; ++n) {
        accZ[n] = __builtin_amdgcn_mfma_f32_16x16x32_bf16(a, ubz[n][ks], accZ[n], 0, 0, 0);
        accR[n] = __builtin_amdgcn_mfma_f32_16x16x32_bf16(a, ubr[n][ks], accR[n], 0, 0, 0);
      }
    }

    // ---- issue xh + dec(t+1) loads (consumed after H MFMAs) ----
    float xhv[4][4], decv[4];
    #pragma unroll
    for (int n = 0; n < 4; ++n) {
      const int col = w * 64 + n * 16 + p;
      #pragma unroll
      for (int e = 0; e < 4; ++e) xhv[n][e] = out[rb[e] + col];
    }
    #pragma unroll
    for (int e = 0; e < 4; ++e)
      decv[e] = (t + 1 < Tt) ? hdecay[(size_t)(b0 + 4 * q + e) * Tt + t + 1] : 0.f;

    // ---- EW-ZR: gates z, r; write bf16(r*h_dec) into Ard ----
    float zz[4][4];
    #pragma unroll
    for (int n = 0; n < 4; ++n) {
      const int c = w * 64 + n * 16 + p;   // this lane's col
      #pragma unroll
      for (int e = 0; e < 4; ++e) {
        float zs = xzv[n][e] + accZ[n][e];
        float rs = xrv[n][e] + accR[n][e];
        float z  = 1.f / (1.f + __expf(-zs));
        float r  = 1.f / (1.f + __expf(-rs));
        zz[n][e] = z;
        float rh = r * hdec[n][e];
        float nb = __shfl_xor(rh, 1, 64);  // neighbor col (p^1)
        if ((p & 1) == 0) {
          unsigned pk = (unsigned)bfbits(rh) | ((unsigned)bfbits(nb) << 16);
          const int row = 4 * q + e;
          const int cb  = (2 * c) ^ ((row & 7) << 4);
          *(unsigned*)(Ard + row * 512 + cb) = pk;
        }
      }
    }
    __syncthreads();   // Ard visible (Ahd readers also done)

    // ---- phase H: acc = A(r*h_dec) @ Uh ----
    f32x4 accH[4];
    #pragma unroll
    for (int n = 0; n < 4; ++n) accH[n] = (f32x4)0.f;
    #pragma unroll
    for (int ks = 0; ks < 8; ++ks) {
      const int cb = (64 * ks + 16 * q) ^ ((p & 7) << 4);
      bf16x8_t a = *(const bf16x8_t*)(Ard + p * 512 + cb);
      #pragma unroll
      for (int n = 0; n < 4; ++n)
        accH[n] = __builtin_amdgcn_mfma_f32_16x16x32_bf16(a, ubh[n][ks], accH[n], 0, 0, 0);
    }

    // ---- EW-H: tanh, combine, store h; write bf16(h_dec(t+1)) into Ahd ----
    #pragma unroll
    for (int n = 0; n < 4; ++n) {
      const int c = w * 64 + n * 16 + p;
      #pragma unroll
      for (int e = 0; e < 4; ++e) {
        float hs = xhv[n][e] + accH[n][e];
        // tanh(x) = 1 - 2/(exp(2x)+1)  (safe at +-inf)
        float ex = __expf(2.f * hs);
        float hp = 1.f - 2.f / (ex + 1.f);
        float z  = zz[n][e];
        float hn = (1.f - z) * hdec[n][e] + z * hp;
        out[rb[e] + c] = hn;
        float hd2 = decv[e] * hn;
        hdec[n][e] = hd2;
        float nb = __shfl_xor(hd2, 1, 64);
        if ((p & 1) == 0) {
          unsigned pk = (unsigned)bfbits(hd2) | ((unsigned)bfbits(nb) << 16);
          const int row = 4 * q + e;
          const int cb  = (2 * c) ^ ((row & 7) << 4);
          *(unsigned*)(Ahd + row * 512 + cb) = pk;
        }
      }
    }
    __syncthreads();   // Ahd(t+1) visible
  }
}

// ---------------------------------------------------------------------------
extern "C" void kernel_launch(void* const* d_in, const int* in_sizes, int n_in,
                              void* d_out, int out_size, void* d_ws, size_t ws_size,
                              hipStream_t stream) {
  const float* x   = (const float*)d_in[0];
  const float* hdc = (const float*)d_in[1];
  const float* Wr  = (const float*)d_in[2];
  const float* Wz  = (const float*)d_in[3];
  const float* Wh  = (const float*)d_in[4];
  const float* Ur  = (const float*)d_in[5];
  const float* Uz  = (const float*)d_in[6];
  const float* Uh  = (const float*)d_in[7];
  const float* br  = (const float*)d_in[8];
  const float* bz  = (const float*)d_in[9];
  const float* bh  = (const float*)d_in[10];
  float* out = (float*)d_out;

  const size_t bth = (size_t)Bb * Tt * Hh;
  dim3 pgrid(2048), pblk(256);

  proj_kernel<false><<<pgrid, pblk, 0, stream>>>(x, Wh, bh, (void*)out);

  if (ws_size >= bth * 2 * sizeof(float)) {
    float* wsz = (float*)d_ws;
    float* wsr = wsz + bth;
    proj_kernel<false><<<pgrid, pblk, 0, stream>>>(x, Wz, bz, (void*)wsz);
    proj_kernel<false><<<pgrid, pblk, 0, stream>>>(x, Wr, br, (void*)wsr);
    gru_scan_mfma<false><<<dim3(16), dim3(256), 0, stream>>>(
        (const void*)wsz, (const void*)wsr, hdc, Uz, Ur, Uh, out);
  } else if (ws_size >= bth * 2 * sizeof(__hip_bfloat16)) {
    __hip_bfloat16* wsz = (__hip_bfloat16*)d_ws;
    __hip_bfloat16* wsr = wsz + bth;
    proj_kernel<true><<<pgrid, pblk, 0, stream>>>(x, Wz, bz, (void*)wsz);
    proj_kernel<true><<<pgrid, pblk, 0, stream>>>(x, Wr, br, (void*)wsr);
    gru_scan_mfma<true><<<dim3(16), dim3(256), 0, stream>>>(
        (const void*)wsz, (const void*)wsr, hdc, Uz, Ur, Uh, out);
  }
}

// Round 4
// 2164.837 us; speedup vs baseline: 4.8053x; 1.9830x over previous
//
#include <hip/hip_runtime.h>
#include <hip/hip_bf16.h>

// GRU-D layer: B=256, T=512, D=128, H=256, fp32.
// Phase 1: xg = x @ Wg + bg (3x GEMM). xh -> d_out, xz/xr -> d_ws.
// Phase 2 (R4): MFMA scan, 256 blocks x 1 batch (R3 was 16 blocks x 16
//   batches -> 0.76% occupancy, chip idle). Per-wave MFMA work per step is
//   independent of batches/block, so 1 batch/block is free parallelism:
//   all 256 CUs, 16x less stream per block. U (bf16) stays VGPR-resident
//   as MFMA B-fragments (384 regs/thread). xz/xr/xh prefetched one full
//   step ahead into registers (cover ~= whole step >= L2 latency).

static constexpr int Bb = 256;
static constexpr int Tt = 512;
static constexpr int Dd = 128;
static constexpr int Hh = 256;

typedef short bf16x8_t __attribute__((ext_vector_type(8)));
typedef float f32x4 __attribute__((ext_vector_type(4)));

// ---------------------------------------------------------------------------
// Phase 1 GEMM (unchanged from R1)
// ---------------------------------------------------------------------------
template<bool BF16OUT>
__global__ __launch_bounds__(256) void proj_kernel(
    const float* __restrict__ x, const float* __restrict__ W,
    const float* __restrict__ bias, void* __restrict__ outv)
{
  __shared__ float xT[Dd][68];
  __shared__ float wS[16][Hh];

  const int tid = threadIdx.x;
  const int ty = tid >> 5;
  const int tx = tid & 31;
  const size_t brow = (size_t)blockIdx.x * 64;
  const float* xp = x + brow * Dd;

  #pragma unroll
  for (int it = 0; it < 8; ++it) {
    int idx = it * 256 + tid;
    int row = idx & 63;
    int kq  = idx >> 6;
    float4 v = *(const float4*)(xp + row * Dd + kq * 4);
    xT[kq * 4 + 0][row] = v.x;
    xT[kq * 4 + 1][row] = v.y;
    xT[kq * 4 + 2][row] = v.z;
    xT[kq * 4 + 3][row] = v.w;
  }

  float bv[8];
  *(float4*)&bv[0] = *(const float4*)(bias + tx * 8);
  *(float4*)&bv[4] = *(const float4*)(bias + tx * 8 + 4);

  float acc[8][8];
  #pragma unroll
  for (int i = 0; i < 8; ++i)
    #pragma unroll
    for (int jj = 0; jj < 8; ++jj) acc[i][jj] = 0.f;

  for (int s = 0; s < 8; ++s) {
    #pragma unroll
    for (int it = 0; it < 4; ++it) {
      int idx = it * 256 + tid;
      int kr = idx >> 6;
      int cq = idx & 63;
      *(float4*)&wS[kr][cq * 4] =
          *(const float4*)(W + (size_t)(s * 16 + kr) * Hh + cq * 4);
    }
    __syncthreads();

    #pragma unroll
    for (int kk = 0; kk < 16; ++kk) {
      const int k = s * 16 + kk;
      float xv[8], wv[8];
      *(float4*)&xv[0] = *(const float4*)&xT[k][ty * 8];
      *(float4*)&xv[4] = *(const float4*)&xT[k][ty * 8 + 4];
      *(float4*)&wv[0] = *(const float4*)&wS[kk][tx * 8];
      *(float4*)&wv[4] = *(const float4*)&wS[kk][tx * 8 + 4];
      #pragma unroll
      for (int i = 0; i < 8; ++i)
        #pragma unroll
        for (int jj = 0; jj < 8; ++jj)
          acc[i][jj] = fmaf(xv[i], wv[jj], acc[i][jj]);
    }
    __syncthreads();
  }

  if (!BF16OUT) {
    float* of = (float*)outv;
    #pragma unroll
    for (int i = 0; i < 8; ++i) {
      size_t ro = (brow + (size_t)ty * 8 + i) * Hh + tx * 8;
      float4 a{acc[i][0] + bv[0], acc[i][1] + bv[1],
               acc[i][2] + bv[2], acc[i][3] + bv[3]};
      float4 c{acc[i][4] + bv[4], acc[i][5] + bv[5],
               acc[i][6] + bv[6], acc[i][7] + bv[7]};
      *(float4*)(of + ro) = a;
      *(float4*)(of + ro + 4) = c;
    }
  } else {
    __hip_bfloat16* ob = (__hip_bfloat16*)outv;
    #pragma unroll
    for (int i = 0; i < 8; ++i) {
      size_t ro = (brow + (size_t)ty * 8 + i) * Hh + tx * 8;
      __hip_bfloat16 tmp[8];
      #pragma unroll
      for (int jj = 0; jj < 8; ++jj)
        tmp[jj] = __float2bfloat16(acc[i][jj] + bv[jj]);
      *(uint4*)(ob + ro) = *(uint4*)tmp;
    }
  }
}

// ---------------------------------------------------------------------------
// Phase 2: MFMA scan, 1 batch per block
// ---------------------------------------------------------------------------
__device__ __forceinline__ unsigned short bfbits(float f) {
  __hip_bfloat16 h = __float2bfloat16(f);
  return *reinterpret_cast<unsigned short*>(&h);
}

// B fragment (verified by R3 refcheck): lane holds B[k][col],
// col = c0 + (lane&15), k = 32*ks + 8*(lane>>4) + i, i=0..7.
__device__ __forceinline__ bf16x8_t load_ufrag(
    const float* __restrict__ U, int c0, int ks, int lane)
{
  const int col = c0 + (lane & 15);
  const int kb  = 32 * ks + 8 * (lane >> 4);
  bf16x8_t v;
  #pragma unroll
  for (int i = 0; i < 8; ++i)
    v[i] = (short)bfbits(U[(size_t)(kb + i) * Hh + col]);
  return v;
}

template<bool PROJBF16>
__global__ __launch_bounds__(256, 1) void gru_scan_mfma(
    const void* __restrict__ xz_v, const void* __restrict__ xr_v,
    const float* __restrict__ hdecay,
    const float* __restrict__ Uz, const float* __restrict__ Ur,
    const float* __restrict__ Uh, float* __restrict__ out)
{
  const int tid  = threadIdx.x;
  const int lane = tid & 63;
  const int w    = tid >> 6;        // wave 0..3 -> cols [64w, 64w+64)
  const int q    = lane >> 4;       // 0..3
  const int p    = lane & 15;
  const int b    = blockIdx.x;      // ONE batch per block

  // A buffers: [16 rows][256 cols] bf16, XOR-swizzled (byte ^= (row&7)<<4).
  // Only row 0 (the batch) is ever nonzero; rows 1-15 stay zero forever.
  __shared__ __align__(16) char Ahd[16 * 512];
  __shared__ __align__(16) char Ard[16 * 512];

  // ---- U into registers as bf16 B-fragments: 3*4*8 = 96 x bf16x8 ----
  bf16x8_t ubz[4][8], ubr[4][8], ubh[4][8];
  #pragma unroll
  for (int n = 0; n < 4; ++n) {
    const int c0 = w * 64 + n * 16;
    #pragma unroll
    for (int ks = 0; ks < 8; ++ks) {
      ubz[n][ks] = load_ufrag(Uz, c0, ks, lane);
      ubr[n][ks] = load_ufrag(Ur, c0, ks, lane);
      ubh[n][ks] = load_ufrag(Uh, c0, ks, lane);
    }
  }

  // zero BOTH A buffers entirely (rows 1-15 must be zero for all time)
  #pragma unroll
  for (int i = 0; i < 8; ++i) {
    ((unsigned*)Ahd)[tid + 256 * i] = 0u;
    ((unsigned*)Ard)[tid + 256 * i] = 0u;
  }

  const float* xzf = (const float*)xz_v;
  const float* xrf = (const float*)xr_v;
  const __hip_bfloat16* xzb = (const __hip_bfloat16*)xz_v;
  const __hip_bfloat16* xrb = (const __hip_bfloat16*)xr_v;

  const size_t bbase = (size_t)b * Tt * Hh;   // batch row base
  const int    hbase = b * Tt;                // hdecay base

  float hdec_r[4] = {0.f, 0.f, 0.f, 0.f};     // h_dec at this lane's cols (q==0)
  float xz_c[4], xr_c[4], xh_c[4];            // current-step inputs (q==0)
  float dec_n = 0.f;                          // hdecay[t+1]

  // prologue: load t=0 inputs + hdecay[1]
  if (q == 0) {
    #pragma unroll
    for (int n = 0; n < 4; ++n) {
      const int col = w * 64 + n * 16 + p;
      if (PROJBF16) {
        xz_c[n] = __bfloat162float(xzb[bbase + col]);
        xr_c[n] = __bfloat162float(xrb[bbase + col]);
      } else {
        xz_c[n] = xzf[bbase + col];
        xr_c[n] = xrf[bbase + col];
      }
      xh_c[n] = out[bbase + col];
    }
    dec_n = hdecay[hbase + 1];
  }
  __syncthreads();   // A zeros visible

  for (int t = 0; t < Tt; ++t) {
    // ---- prefetch step t+1 inputs (clamped; junk at t=Tt-1, never used) ----
    float xz_n[4], xr_n[4], xh_n[4];
    float dec_n2 = 0.f;
    {
      const int tp = (t + 1 < Tt) ? t + 1 : Tt - 1;
      const int tq = (t + 2 < Tt) ? t + 2 : Tt - 1;
      if (q == 0) {
        const size_t bp = bbase + (size_t)tp * Hh;
        #pragma unroll
        for (int n = 0; n < 4; ++n) {
          const int col = w * 64 + n * 16 + p;
          if (PROJBF16) {
            xz_n[n] = __bfloat162float(xzb[bp + col]);
            xr_n[n] = __bfloat162float(xrb[bp + col]);
          } else {
            xz_n[n] = xzf[bp + col];
            xr_n[n] = xrf[bp + col];
          }
          xh_n[n] = out[bp + col];
        }
        dec_n2 = hdecay[hbase + tq];
      }
    }

    // ---- phase ZR: C = A(h_dec) @ U{z,r} ----
    f32x4 accZ[4], accR[4];
    #pragma unroll
    for (int n = 0; n < 4; ++n) { accZ[n] = (f32x4)0.f; accR[n] = (f32x4)0.f; }
    #pragma unroll
    for (int ks = 0; ks < 8; ++ks) {
      const int cb = (64 * ks + 16 * q) ^ ((p & 7) << 4);
      bf16x8_t a = *(const bf16x8_t*)(Ahd + p * 512 + cb);
      #pragma unroll
      for (int n = 0; n < 4; ++n) {
        accZ[n] = __builtin_amdgcn_mfma_f32_16x16x32_bf16(a, ubz[n][ks], accZ[n], 0, 0, 0);
        accR[n] = __builtin_amdgcn_mfma_f32_16x16x32_bf16(a, ubr[n][ks], accR[n], 0, 0, 0);
      }
    }

    // ---- EW-ZR (row 0 = q==0, reg 0): gates z,r; write bf16(r*h_dec) ----
    float zg[4];
    if (q == 0) {
      #pragma unroll
      for (int n = 0; n < 4; ++n) {
        const int c = w * 64 + n * 16 + p;
        float zs = xz_c[n] + accZ[n][0];
        float rs = xr_c[n] + accR[n][0];
        zg[n] = 1.f / (1.f + __expf(-zs));
        float r = 1.f / (1.f + __expf(-rs));
        float rh = r * hdec_r[n];
        float nb = __shfl_xor(rh, 1, 64);   // partner col p^1 (within q==0)
        if ((p & 1) == 0) {
          unsigned pk = (unsigned)bfbits(rh) | ((unsigned)bfbits(nb) << 16);
          *(unsigned*)(Ard + 2 * c) = pk;   // row 0: swizzle is identity
        }
      }
    }
    __syncthreads();   // Ard visible

    // ---- phase H: C = A(r*h_dec) @ Uh ----
    f32x4 accH[4];
    #pragma unroll
    for (int n = 0; n < 4; ++n) accH[n] = (f32x4)0.f;
    #pragma unroll
    for (int ks = 0; ks < 8; ++ks) {
      const int cb = (64 * ks + 16 * q) ^ ((p & 7) << 4);
      bf16x8_t a = *(const bf16x8_t*)(Ard + p * 512 + cb);
      #pragma unroll
      for (int n = 0; n < 4; ++n)
        accH[n] = __builtin_amdgcn_mfma_f32_16x16x32_bf16(a, ubh[n][ks], accH[n], 0, 0, 0);
    }

    // ---- EW-H: tanh, combine, store h_t; write bf16(h_dec(t+1)) ----
    if (q == 0) {
      const size_t ob = bbase + (size_t)t * Hh;
      #pragma unroll
      for (int n = 0; n < 4; ++n) {
        const int c = w * 64 + n * 16 + p;
        float hs = xh_c[n] + accH[n][0];
        float ex = __expf(2.f * hs);          // tanh = 1 - 2/(e^{2x}+1)
        float hp = 1.f - 2.f / (ex + 1.f);
        float hn = (1.f - zg[n]) * hdec_r[n] + zg[n] * hp;
        out[ob + c] = hn;
        float hd2 = dec_n * hn;
        hdec_r[n] = hd2;
        float nb = __shfl_xor(hd2, 1, 64);
        if ((p & 1) == 0) {
          unsigned pk = (unsigned)bfbits(hd2) | ((unsigned)bfbits(nb) << 16);
          *(unsigned*)(Ahd + 2 * c) = pk;     // row 0
        }
      }
      // rotate prefetch
      #pragma unroll
      for (int n = 0; n < 4; ++n) {
        xz_c[n] = xz_n[n]; xr_c[n] = xr_n[n]; xh_c[n] = xh_n[n];
      }
      dec_n = dec_n2;
    }
    __syncthreads();   // Ahd(t+1) visible
  }
}

// ---------------------------------------------------------------------------
extern "C" void kernel_launch(void* const* d_in, const int* in_sizes, int n_in,
                              void* d_out, int out_size, void* d_ws, size_t ws_size,
                              hipStream_t stream) {
  const float* x   = (const float*)d_in[0];
  const float* hdc = (const float*)d_in[1];
  const float* Wr  = (const float*)d_in[2];
  const float* Wz  = (const float*)d_in[3];
  const float* Wh  = (const float*)d_in[4];
  const float* Ur  = (const float*)d_in[5];
  const float* Uz  = (const float*)d_in[6];
  const float* Uh  = (const float*)d_in[7];
  const float* br  = (const float*)d_in[8];
  const float* bz  = (const float*)d_in[9];
  const float* bh  = (const float*)d_in[10];
  float* out = (float*)d_out;

  const size_t bth = (size_t)Bb * Tt * Hh;
  dim3 pgrid(2048), pblk(256);

  proj_kernel<false><<<pgrid, pblk, 0, stream>>>(x, Wh, bh, (void*)out);

  if (ws_size >= bth * 2 * sizeof(float)) {
    float* wsz = (float*)d_ws;
    float* wsr = wsz + bth;
    proj_kernel<false><<<pgrid, pblk, 0, stream>>>(x, Wz, bz, (void*)wsz);
    proj_kernel<false><<<pgrid, pblk, 0, stream>>>(x, Wr, br, (void*)wsr);
    gru_scan_mfma<false><<<dim3(Bb), dim3(256), 0, stream>>>(
        (const void*)wsz, (const void*)wsr, hdc, Uz, Ur, Uh, out);
  } else if (ws_size >= bth * 2 * sizeof(__hip_bfloat16)) {
    __hip_bfloat16* wsz = (__hip_bfloat16*)d_ws;
    __hip_bfloat16* wsr = wsz + bth;
    proj_kernel<true><<<pgrid, pblk, 0, stream>>>(x, Wz, bz, (void*)wsz);
    proj_kernel<true><<<pgrid, pblk, 0, stream>>>(x, Wr, br, (void*)wsr);
    gru_scan_mfma<true><<<dim3(Bb), dim3(256), 0, stream>>>(
        (const void*)wsz, (const void*)wsr, hdc, Uz, Ur, Uh, out);
  }
}

// Round 5
// 2157.794 us; speedup vs baseline: 4.8210x; 1.0033x over previous
//
#include <hip/hip_runtime.h>
#include <hip/hip_bf16.h>

// GRU-D layer: B=256, T=512, D=128, H=256, fp32.
// Phase 1: xg = x @ Wg + bg (3x GEMM). xh -> d_out, xz/xr -> d_ws.
// Phase 2 (R5): MFMA scan, 256 blocks x 1 batch, now 8 waves x 2 n-tiles
//   (R4 was 4 waves x 4 n-tiles: U = 384 regs/thread > 256 arch VGPRs ->
//   AGPR spill-moves before every MFMA (VALUBusy 33% of junk) + 1 wave/SIMD
//   (no TLP). 192 U regs/thread fits arch VGPRs; 2 waves/SIMD hide latency.)

static constexpr int Bb = 256;
static constexpr int Tt = 512;
static constexpr int Dd = 128;
static constexpr int Hh = 256;

typedef short bf16x8_t __attribute__((ext_vector_type(8)));
typedef float f32x4 __attribute__((ext_vector_type(4)));

// ---------------------------------------------------------------------------
// Phase 1 GEMM (unchanged from R1)
// ---------------------------------------------------------------------------
template<bool BF16OUT>
__global__ __launch_bounds__(256) void proj_kernel(
    const float* __restrict__ x, const float* __restrict__ W,
    const float* __restrict__ bias, void* __restrict__ outv)
{
  __shared__ float xT[Dd][68];
  __shared__ float wS[16][Hh];

  const int tid = threadIdx.x;
  const int ty = tid >> 5;
  const int tx = tid & 31;
  const size_t brow = (size_t)blockIdx.x * 64;
  const float* xp = x + brow * Dd;

  #pragma unroll
  for (int it = 0; it < 8; ++it) {
    int idx = it * 256 + tid;
    int row = idx & 63;
    int kq  = idx >> 6;
    float4 v = *(const float4*)(xp + row * Dd + kq * 4);
    xT[kq * 4 + 0][row] = v.x;
    xT[kq * 4 + 1][row] = v.y;
    xT[kq * 4 + 2][row] = v.z;
    xT[kq * 4 + 3][row] = v.w;
  }

  float bv[8];
  *(float4*)&bv[0] = *(const float4*)(bias + tx * 8);
  *(float4*)&bv[4] = *(const float4*)(bias + tx * 8 + 4);

  float acc[8][8];
  #pragma unroll
  for (int i = 0; i < 8; ++i)
    #pragma unroll
    for (int jj = 0; jj < 8; ++jj) acc[i][jj] = 0.f;

  for (int s = 0; s < 8; ++s) {
    #pragma unroll
    for (int it = 0; it < 4; ++it) {
      int idx = it * 256 + tid;
      int kr = idx >> 6;
      int cq = idx & 63;
      *(float4*)&wS[kr][cq * 4] =
          *(const float4*)(W + (size_t)(s * 16 + kr) * Hh + cq * 4);
    }
    __syncthreads();

    #pragma unroll
    for (int kk = 0; kk < 16; ++kk) {
      const int k = s * 16 + kk;
      float xv[8], wv[8];
      *(float4*)&xv[0] = *(const float4*)&xT[k][ty * 8];
      *(float4*)&xv[4] = *(const float4*)&xT[k][ty * 8 + 4];
      *(float4*)&wv[0] = *(const float4*)&wS[kk][tx * 8];
      *(float4*)&wv[4] = *(const float4*)&wS[kk][tx * 8 + 4];
      #pragma unroll
      for (int i = 0; i < 8; ++i)
        #pragma unroll
        for (int jj = 0; jj < 8; ++jj)
          acc[i][jj] = fmaf(xv[i], wv[jj], acc[i][jj]);
    }
    __syncthreads();
  }

  if (!BF16OUT) {
    float* of = (float*)outv;
    #pragma unroll
    for (int i = 0; i < 8; ++i) {
      size_t ro = (brow + (size_t)ty * 8 + i) * Hh + tx * 8;
      float4 a{acc[i][0] + bv[0], acc[i][1] + bv[1],
               acc[i][2] + bv[2], acc[i][3] + bv[3]};
      float4 c{acc[i][4] + bv[4], acc[i][5] + bv[5],
               acc[i][6] + bv[6], acc[i][7] + bv[7]};
      *(float4*)(of + ro) = a;
      *(float4*)(of + ro + 4) = c;
    }
  } else {
    __hip_bfloat16* ob = (__hip_bfloat16*)outv;
    #pragma unroll
    for (int i = 0; i < 8; ++i) {
      size_t ro = (brow + (size_t)ty * 8 + i) * Hh + tx * 8;
      __hip_bfloat16 tmp[8];
      #pragma unroll
      for (int jj = 0; jj < 8; ++jj)
        tmp[jj] = __float2bfloat16(acc[i][jj] + bv[jj]);
      *(uint4*)(ob + ro) = *(uint4*)tmp;
    }
  }
}

// ---------------------------------------------------------------------------
// Phase 2: MFMA scan, 1 batch/block, 8 waves x 2 n-tiles
// ---------------------------------------------------------------------------
__device__ __forceinline__ unsigned short bfbits(float f) {
  __hip_bfloat16 h = __float2bfloat16(f);
  return *reinterpret_cast<unsigned short*>(&h);
}

// B fragment (verified R3/R4): lane holds B[k][col],
// col = c0 + (lane&15), k = 32*ks + 8*(lane>>4) + i, i=0..7.
__device__ __forceinline__ bf16x8_t load_ufrag(
    const float* __restrict__ U, int c0, int ks, int lane)
{
  const int col = c0 + (lane & 15);
  const int kb  = 32 * ks + 8 * (lane >> 4);
  bf16x8_t v;
  #pragma unroll
  for (int i = 0; i < 8; ++i)
    v[i] = (short)bfbits(U[(size_t)(kb + i) * Hh + col]);
  return v;
}

template<bool PROJBF16>
__global__ __launch_bounds__(512, 2) void gru_scan_mfma(
    const void* __restrict__ xz_v, const void* __restrict__ xr_v,
    const float* __restrict__ hdecay,
    const float* __restrict__ Uz, const float* __restrict__ Ur,
    const float* __restrict__ Uh, float* __restrict__ out)
{
  const int tid  = threadIdx.x;
  const int lane = tid & 63;
  const int w    = tid >> 6;        // wave 0..7 -> cols [32w, 32w+32)
  const int q    = lane >> 4;       // 0..3
  const int p    = lane & 15;
  const int b    = blockIdx.x;      // ONE batch per block

  // A buffers: [16 rows][256 cols] bf16, XOR-swizzled (byte ^= (row&7)<<4).
  // Only row 0 nonzero; rows 1-15 stay zero forever.
  __shared__ __align__(16) char Ahd[16 * 512];
  __shared__ __align__(16) char Ard[16 * 512];

  // ---- U -> registers as bf16 B-fragments: 3*2*8 = 48 x bf16x8 = 192 VGPR ----
  bf16x8_t ubz[2][8], ubr[2][8], ubh[2][8];
  #pragma unroll
  for (int n = 0; n < 2; ++n) {
    const int c0 = w * 32 + n * 16;
    #pragma unroll
    for (int ks = 0; ks < 8; ++ks) {
      ubz[n][ks] = load_ufrag(Uz, c0, ks, lane);
      ubr[n][ks] = load_ufrag(Ur, c0, ks, lane);
      ubh[n][ks] = load_ufrag(Uh, c0, ks, lane);
    }
  }

  // zero BOTH A buffers (512 threads x 4 dwords each buffer)
  #pragma unroll
  for (int i = 0; i < 4; ++i) {
    ((unsigned*)Ahd)[tid + 512 * i] = 0u;
    ((unsigned*)Ard)[tid + 512 * i] = 0u;
  }

  const float* xzf = (const float*)xz_v;
  const float* xrf = (const float*)xr_v;
  const __hip_bfloat16* xzb = (const __hip_bfloat16*)xz_v;
  const __hip_bfloat16* xrb = (const __hip_bfloat16*)xr_v;

  const size_t bbase = (size_t)b * Tt * Hh;
  const int    hbase = b * Tt;

  float hdec_r[2] = {0.f, 0.f};     // h_dec at this lane's 2 cols (q==0)
  float xz_c[2], xr_c[2], xh_c[2];  // current-step inputs (q==0)
  float dec_n = 0.f;                // hdecay[t+1]

  // prologue: t=0 inputs + hdecay[1]
  if (q == 0) {
    #pragma unroll
    for (int n = 0; n < 2; ++n) {
      const int col = w * 32 + n * 16 + p;
      if (PROJBF16) {
        xz_c[n] = __bfloat162float(xzb[bbase + col]);
        xr_c[n] = __bfloat162float(xrb[bbase + col]);
      } else {
        xz_c[n] = xzf[bbase + col];
        xr_c[n] = xrf[bbase + col];
      }
      xh_c[n] = out[bbase + col];
    }
    dec_n = hdecay[hbase + 1];
  }
  __syncthreads();   // A zeros visible

  for (int t = 0; t < Tt; ++t) {
    // ---- prefetch t+1 inputs (clamped; junk at t=Tt-1 never used) ----
    float xz_n[2], xr_n[2], xh_n[2];
    float dec_n2 = 0.f;
    if (q == 0) {
      const int tp = (t + 1 < Tt) ? t + 1 : Tt - 1;
      const int tq = (t + 2 < Tt) ? t + 2 : Tt - 1;
      const size_t bp = bbase + (size_t)tp * Hh;
      #pragma unroll
      for (int n = 0; n < 2; ++n) {
        const int col = w * 32 + n * 16 + p;
        if (PROJBF16) {
          xz_n[n] = __bfloat162float(xzb[bp + col]);
          xr_n[n] = __bfloat162float(xrb[bp + col]);
        } else {
          xz_n[n] = xzf[bp + col];
          xr_n[n] = xrf[bp + col];
        }
        xh_n[n] = out[bp + col];
      }
      dec_n2 = hdecay[hbase + tq];
    }

    // ---- phase ZR: C = A(h_dec) @ U{z,r} ----
    f32x4 accZ[2], accR[2];
    #pragma unroll
    for (int n = 0; n < 2; ++n) { accZ[n] = (f32x4)0.f; accR[n] = (f32x4)0.f; }
    __builtin_amdgcn_s_setprio(1);
    #pragma unroll
    for (int ks = 0; ks < 8; ++ks) {
      const int cb = (64 * ks + 16 * q) ^ ((p & 7) << 4);
      bf16x8_t a = *(const bf16x8_t*)(Ahd + p * 512 + cb);
      #pragma unroll
      for (int n = 0; n < 2; ++n) {
        accZ[n] = __builtin_amdgcn_mfma_f32_16x16x32_bf16(a, ubz[n][ks], accZ[n], 0, 0, 0);
        accR[n] = __builtin_amdgcn_mfma_f32_16x16x32_bf16(a, ubr[n][ks], accR[n], 0, 0, 0);
      }
    }
    __builtin_amdgcn_s_setprio(0);

    // ---- EW-ZR (row 0 = q==0, reg 0): gates; write bf16(r*h_dec) ----
    float zg[2];
    if (q == 0) {
      #pragma unroll
      for (int n = 0; n < 2; ++n) {
        const int c = w * 32 + n * 16 + p;
        float zs = xz_c[n] + accZ[n][0];
        float rs = xr_c[n] + accR[n][0];
        zg[n] = 1.f / (1.f + __expf(-zs));
        float r = 1.f / (1.f + __expf(-rs));
        float rh = r * hdec_r[n];
        float nb = __shfl_xor(rh, 1, 64);   // partner col p^1
        if ((p & 1) == 0) {
          unsigned pk = (unsigned)bfbits(rh) | ((unsigned)bfbits(nb) << 16);
          *(unsigned*)(Ard + 2 * c) = pk;   // row 0: swizzle identity
        }
      }
    }
    __syncthreads();   // Ard visible

    // ---- phase H: C = A(r*h_dec) @ Uh ----
    f32x4 accH[2];
    #pragma unroll
    for (int n = 0; n < 2; ++n) accH[n] = (f32x4)0.f;
    __builtin_amdgcn_s_setprio(1);
    #pragma unroll
    for (int ks = 0; ks < 8; ++ks) {
      const int cb = (64 * ks + 16 * q) ^ ((p & 7) << 4);
      bf16x8_t a = *(const bf16x8_t*)(Ard + p * 512 + cb);
      #pragma unroll
      for (int n = 0; n < 2; ++n)
        accH[n] = __builtin_amdgcn_mfma_f32_16x16x32_bf16(a, ubh[n][ks], accH[n], 0, 0, 0);
    }
    __builtin_amdgcn_s_setprio(0);

    // ---- EW-H: tanh, combine, store h_t; write bf16(h_dec(t+1)) ----
    if (q == 0) {
      const size_t ob = bbase + (size_t)t * Hh;
      #pragma unroll
      for (int n = 0; n < 2; ++n) {
        const int c = w * 32 + n * 16 + p;
        float hs = xh_c[n] + accH[n][0];
        float ex = __expf(2.f * hs);          // tanh = 1 - 2/(e^{2x}+1)
        float hp = 1.f - 2.f / (ex + 1.f);
        float hn = (1.f - zg[n]) * hdec_r[n] + zg[n] * hp;
        out[ob + c] = hn;
        float hd2 = dec_n * hn;
        hdec_r[n] = hd2;
        float nb = __shfl_xor(hd2, 1, 64);
        if ((p & 1) == 0) {
          unsigned pk = (unsigned)bfbits(hd2) | ((unsigned)bfbits(nb) << 16);
          *(unsigned*)(Ahd + 2 * c) = pk;     // row 0
        }
        xz_c[n] = xz_n[n]; xr_c[n] = xr_n[n]; xh_c[n] = xh_n[n];
      }
      dec_n = dec_n2;
    }
    __syncthreads();   // Ahd(t+1) visible
  }
}

// ---------------------------------------------------------------------------
extern "C" void kernel_launch(void* const* d_in, const int* in_sizes, int n_in,
                              void* d_out, int out_size, void* d_ws, size_t ws_size,
                              hipStream_t stream) {
  const float* x   = (const float*)d_in[0];
  const float* hdc = (const float*)d_in[1];
  const float* Wr  = (const float*)d_in[2];
  const float* Wz  = (const float*)d_in[3];
  const float* Wh  = (const float*)d_in[4];
  const float* Ur  = (const float*)d_in[5];
  const float* Uz  = (const float*)d_in[6];
  const float* Uh  = (const float*)d_in[7];
  const float* br  = (const float*)d_in[8];
  const float* bz  = (const float*)d_in[9];
  const float* bh  = (const float*)d_in[10];
  float* out = (float*)d_out;

  const size_t bth = (size_t)Bb * Tt * Hh;
  dim3 pgrid(2048), pblk(256);

  proj_kernel<false><<<pgrid, pblk, 0, stream>>>(x, Wh, bh, (void*)out);

  if (ws_size >= bth * 2 * sizeof(float)) {
    float* wsz = (float*)d_ws;
    float* wsr = wsz + bth;
    proj_kernel<false><<<pgrid, pblk, 0, stream>>>(x, Wz, bz, (void*)wsz);
    proj_kernel<false><<<pgrid, pblk, 0, stream>>>(x, Wr, br, (void*)wsr);
    gru_scan_mfma<false><<<dim3(Bb), dim3(512), 0, stream>>>(
        (const void*)wsz, (const void*)wsr, hdc, Uz, Ur, Uh, out);
  } else if (ws_size >= bth * 2 * sizeof(__hip_bfloat16)) {
    __hip_bfloat16* wsz = (__hip_bfloat16*)d_ws;
    __hip_bfloat16* wsr = wsz + bth;
    proj_kernel<true><<<pgrid, pblk, 0, stream>>>(x, Wz, bz, (void*)wsz);
    proj_kernel<true><<<pgrid, pblk, 0, stream>>>(x, Wr, br, (void*)wsr);
    gru_scan_mfma<true><<<dim3(Bb), dim3(512), 0, stream>>>(
        (const void*)wsz, (const void*)wsr, hdc, Uz, Ur, Uh, out);
  }
}

// Round 6
// 1387.930 us; speedup vs baseline: 7.4952x; 1.5547x over previous
//
#include <hip/hip_runtime.h>
#include <hip/hip_bf16.h>

// GRU-D layer: B=256, T=512, D=128, H=256, fp32.
// Phase 1: xg = x @ Wg + bg (3x GEMM). xh -> d_out, xz/xr -> d_ws.
// Phase 2 (R6): dot2 scan. R5 post-mortem: MFMA A-matrix had 1 nonzero row
//   of 16 -> 94% of matrix-pipe work multiplied zeros. New design: pure
//   VALU v_dot2_f32_f16, 512 thr = 256 cols x 2 k-halves, U as f16 pairs
//   in 192 VGPRs/thread (fits 256-cap; R2's fp32 spill was 384 regs).
//   h_dec/r*h_dec as f16x2 in LDS, wave-uniform broadcast reads.
//   Per thread per step: 192 dot2 = exact FLOP floor, all lanes useful.

static constexpr int Bb = 256;
static constexpr int Tt = 512;
static constexpr int Dd = 128;
static constexpr int Hh = 256;

typedef _Float16 half2_t __attribute__((ext_vector_type(2)));

// ---------------------------------------------------------------------------
// Phase 1 GEMM (unchanged from R1)
// ---------------------------------------------------------------------------
template<bool BF16OUT>
__global__ __launch_bounds__(256) void proj_kernel(
    const float* __restrict__ x, const float* __restrict__ W,
    const float* __restrict__ bias, void* __restrict__ outv)
{
  __shared__ float xT[Dd][68];
  __shared__ float wS[16][Hh];

  const int tid = threadIdx.x;
  const int ty = tid >> 5;
  const int tx = tid & 31;
  const size_t brow = (size_t)blockIdx.x * 64;
  const float* xp = x + brow * Dd;

  #pragma unroll
  for (int it = 0; it < 8; ++it) {
    int idx = it * 256 + tid;
    int row = idx & 63;
    int kq  = idx >> 6;
    float4 v = *(const float4*)(xp + row * Dd + kq * 4);
    xT[kq * 4 + 0][row] = v.x;
    xT[kq * 4 + 1][row] = v.y;
    xT[kq * 4 + 2][row] = v.z;
    xT[kq * 4 + 3][row] = v.w;
  }

  float bv[8];
  *(float4*)&bv[0] = *(const float4*)(bias + tx * 8);
  *(float4*)&bv[4] = *(const float4*)(bias + tx * 8 + 4);

  float acc[8][8];
  #pragma unroll
  for (int i = 0; i < 8; ++i)
    #pragma unroll
    for (int jj = 0; jj < 8; ++jj) acc[i][jj] = 0.f;

  for (int s = 0; s < 8; ++s) {
    #pragma unroll
    for (int it = 0; it < 4; ++it) {
      int idx = it * 256 + tid;
      int kr = idx >> 6;
      int cq = idx & 63;
      *(float4*)&wS[kr][cq * 4] =
          *(const float4*)(W + (size_t)(s * 16 + kr) * Hh + cq * 4);
    }
    __syncthreads();

    #pragma unroll
    for (int kk = 0; kk < 16; ++kk) {
      const int k = s * 16 + kk;
      float xv[8], wv[8];
      *(float4*)&xv[0] = *(const float4*)&xT[k][ty * 8];
      *(float4*)&xv[4] = *(const float4*)&xT[k][ty * 8 + 4];
      *(float4*)&wv[0] = *(const float4*)&wS[kk][tx * 8];
      *(float4*)&wv[4] = *(const float4*)&wS[kk][tx * 8 + 4];
      #pragma unroll
      for (int i = 0; i < 8; ++i)
        #pragma unroll
        for (int jj = 0; jj < 8; ++jj)
          acc[i][jj] = fmaf(xv[i], wv[jj], acc[i][jj]);
    }
    __syncthreads();
  }

  if (!BF16OUT) {
    float* of = (float*)outv;
    #pragma unroll
    for (int i = 0; i < 8; ++i) {
      size_t ro = (brow + (size_t)ty * 8 + i) * Hh + tx * 8;
      float4 a{acc[i][0] + bv[0], acc[i][1] + bv[1],
               acc[i][2] + bv[2], acc[i][3] + bv[3]};
      float4 c{acc[i][4] + bv[4], acc[i][5] + bv[5],
               acc[i][6] + bv[6], acc[i][7] + bv[7]};
      *(float4*)(of + ro) = a;
      *(float4*)(of + ro + 4) = c;
    }
  } else {
    __hip_bfloat16* ob = (__hip_bfloat16*)outv;
    #pragma unroll
    for (int i = 0; i < 8; ++i) {
      size_t ro = (brow + (size_t)ty * 8 + i) * Hh + tx * 8;
      __hip_bfloat16 tmp[8];
      #pragma unroll
      for (int jj = 0; jj < 8; ++jj)
        tmp[jj] = __float2bfloat16(acc[i][jj] + bv[jj]);
      *(uint4*)(ob + ro) = *(uint4*)tmp;
    }
  }
}

// ---------------------------------------------------------------------------
// Phase 2: dot2 scan
// ---------------------------------------------------------------------------
__device__ __forceinline__ float dot2f(unsigned a, unsigned b, float c) {
  half2_t av, bv;
  __builtin_memcpy(&av, &a, 4);
  __builtin_memcpy(&bv, &b, 4);
#if __has_builtin(__builtin_amdgcn_fdot2)
  return __builtin_amdgcn_fdot2(av, bv, c, false);
#else
  return fmaf((float)av[1], (float)bv[1], fmaf((float)av[0], (float)bv[0], c));
#endif
}

__device__ __forceinline__ unsigned packh2(float lo, float hi) {
  half2_t hv;
  hv[0] = (_Float16)lo;
  hv[1] = (_Float16)hi;
  unsigned u;
  __builtin_memcpy(&u, &hv, 4);
  return u;
}

template<bool PROJBF16>
__global__ __launch_bounds__(512, 2) void gru_scan_dot2(
    const void* __restrict__ xz_v, const void* __restrict__ xr_v,
    const float* __restrict__ hdecay,
    const float* __restrict__ Uz, const float* __restrict__ Ur,
    const float* __restrict__ Uh, float* __restrict__ out)
{
  const int tid  = threadIdx.x;
  const int j    = tid & (Hh - 1);   // output column
  const int half = tid >> 8;         // 0: waves 0-3, 1: waves 4-7 (k-half)
  const int k0   = half << 7;        // 0 or 128
  const int b    = blockIdx.x;       // one batch per block

  __shared__ unsigned hdp[128];      // f16x2 pairs of h_dec (256 f16)
  __shared__ unsigned rhp[128];      // f16x2 pairs of r*h_dec
  __shared__ float pz1[Hh], pr1[Hh], ph1[Hh];   // half-1 partials

  // ---- U column-halves into regs as f16 pairs: 3 x 64 dwords = 192 VGPR ----
  unsigned uz[64], ur[64], uh[64];
  {
    const float* uzp = Uz + (size_t)k0 * Hh + j;
    const float* urp = Ur + (size_t)k0 * Hh + j;
    const float* uhp = Uh + (size_t)k0 * Hh + j;
    #pragma unroll
    for (int m = 0; m < 64; ++m) {
      uz[m] = packh2(uzp[(size_t)(2 * m) * Hh], uzp[(size_t)(2 * m + 1) * Hh]);
      ur[m] = packh2(urp[(size_t)(2 * m) * Hh], urp[(size_t)(2 * m + 1) * Hh]);
      uh[m] = packh2(uhp[(size_t)(2 * m) * Hh], uhp[(size_t)(2 * m + 1) * Hh]);
    }
  }

  if (tid < 128) hdp[tid] = 0u;      // h0 = 0

  const float* xzf = (const float*)xz_v;
  const float* xrf = (const float*)xr_v;
  const __hip_bfloat16* xzb = (const __hip_bfloat16*)xz_v;
  const __hip_bfloat16* xrb = (const __hip_bfloat16*)xr_v;

  const size_t bbase = (size_t)b * Tt * Hh;
  const int    hbase = b * Tt;

  float hd = 0.f;                    // h_dec[j] (half0 only meaningful)
  float xz_c = 0.f, xr_c = 0.f, xh_c = 0.f, dec_n = 0.f;

  if (half == 0) {                   // prologue: t=0 inputs + hdecay[1]
    if (PROJBF16) {
      xz_c = __bfloat162float(xzb[bbase + j]);
      xr_c = __bfloat162float(xrb[bbase + j]);
    } else {
      xz_c = xzf[bbase + j];
      xr_c = xrf[bbase + j];
    }
    xh_c = out[bbase + j];
    dec_n = hdecay[hbase + 1];
  }
  __syncthreads();

  for (int t = 0; t < Tt; ++t) {
    // ---- prefetch t+1 (half0; clamped at end, junk unused) ----
    float xz_n = 0.f, xr_n = 0.f, xh_n = 0.f, dec_n2 = 0.f;
    if (half == 0) {
      const int tp = (t + 1 < Tt) ? t + 1 : Tt - 1;
      const int tq = (t + 2 < Tt) ? t + 2 : Tt - 1;
      const size_t bp = bbase + (size_t)tp * Hh + j;
      if (PROJBF16) {
        xz_n = __bfloat162float(xzb[bp]);
        xr_n = __bfloat162float(xrb[bp]);
      } else {
        xz_n = xzf[bp];
        xr_n = xrf[bp];
      }
      xh_n = out[bp];
      dec_n2 = hdecay[hbase + tq];
    }

    // ---- A: z/r dot over own k-half (h pairs broadcast from LDS) ----
    float az0 = 0.f, az1 = 0.f, ar0 = 0.f, ar1 = 0.f;
    #pragma unroll
    for (int m8 = 0; m8 < 64; m8 += 8) {
      uint4 ha = *(const uint4*)&hdp[(half << 6) + m8];
      uint4 hb = *(const uint4*)&hdp[(half << 6) + m8 + 4];
      az0 = dot2f(ha.x, uz[m8 + 0], az0);
      az0 = dot2f(ha.y, uz[m8 + 1], az0);
      az0 = dot2f(ha.z, uz[m8 + 2], az0);
      az0 = dot2f(ha.w, uz[m8 + 3], az0);
      az1 = dot2f(hb.x, uz[m8 + 4], az1);
      az1 = dot2f(hb.y, uz[m8 + 5], az1);
      az1 = dot2f(hb.z, uz[m8 + 6], az1);
      az1 = dot2f(hb.w, uz[m8 + 7], az1);
      ar0 = dot2f(ha.x, ur[m8 + 0], ar0);
      ar0 = dot2f(ha.y, ur[m8 + 1], ar0);
      ar0 = dot2f(ha.z, ur[m8 + 2], ar0);
      ar0 = dot2f(ha.w, ur[m8 + 3], ar0);
      ar1 = dot2f(hb.x, ur[m8 + 4], ar1);
      ar1 = dot2f(hb.y, ur[m8 + 5], ar1);
      ar1 = dot2f(hb.z, ur[m8 + 6], ar1);
      ar1 = dot2f(hb.w, ur[m8 + 7], ar1);
    }
    if (half) { pz1[j] = az0 + az1; pr1[j] = ar0 + ar1; }
    __syncthreads();

    // ---- B: gates (half0); write f16 pairs of r*h_dec ----
    float z = 0.f;
    if (half == 0) {
      float zs = xz_c + az0 + az1 + pz1[j];
      float rs = xr_c + ar0 + ar1 + pr1[j];
      z = 1.f / (1.f + __expf(-zs));
      float r = 1.f / (1.f + __expf(-rs));
      float rh = r * hd;
      float nb = __shfl_xor(rh, 1, 64);     // partner col j^1 (same wave)
      if ((j & 1) == 0) rhp[j >> 1] = packh2(rh, nb);
    }
    __syncthreads();

    // ---- C: h dot over own k-half ----
    float ah0 = 0.f, ah1 = 0.f;
    #pragma unroll
    for (int m8 = 0; m8 < 64; m8 += 8) {
      uint4 ra = *(const uint4*)&rhp[(half << 6) + m8];
      uint4 rb = *(const uint4*)&rhp[(half << 6) + m8 + 4];
      ah0 = dot2f(ra.x, uh[m8 + 0], ah0);
      ah0 = dot2f(ra.y, uh[m8 + 1], ah0);
      ah0 = dot2f(ra.z, uh[m8 + 2], ah0);
      ah0 = dot2f(ra.w, uh[m8 + 3], ah0);
      ah1 = dot2f(rb.x, uh[m8 + 4], ah1);
      ah1 = dot2f(rb.y, uh[m8 + 5], ah1);
      ah1 = dot2f(rb.z, uh[m8 + 6], ah1);
      ah1 = dot2f(rb.w, uh[m8 + 7], ah1);
    }
    if (half) ph1[j] = ah0 + ah1;
    __syncthreads();

    // ---- D: tanh, combine, store h_t; write f16 pairs of h_dec(t+1) ----
    if (half == 0) {
      float hs = xh_c + ah0 + ah1 + ph1[j];
      float ex = __expf(2.f * hs);          // tanh = 1 - 2/(e^{2x}+1)
      float hp = 1.f - 2.f / (ex + 1.f);
      float hn = (1.f - z) * hd + z * hp;
      out[bbase + (size_t)t * Hh + j] = hn;
      hd = dec_n * hn;
      float nb = __shfl_xor(hd, 1, 64);
      if ((j & 1) == 0) hdp[j >> 1] = packh2(hd, nb);
      xz_c = xz_n; xr_c = xr_n; xh_c = xh_n; dec_n = dec_n2;
    }
    __syncthreads();
  }
}

// ---------------------------------------------------------------------------
extern "C" void kernel_launch(void* const* d_in, const int* in_sizes, int n_in,
                              void* d_out, int out_size, void* d_ws, size_t ws_size,
                              hipStream_t stream) {
  const float* x   = (const float*)d_in[0];
  const float* hdc = (const float*)d_in[1];
  const float* Wr  = (const float*)d_in[2];
  const float* Wz  = (const float*)d_in[3];
  const float* Wh  = (const float*)d_in[4];
  const float* Ur  = (const float*)d_in[5];
  const float* Uz  = (const float*)d_in[6];
  const float* Uh  = (const float*)d_in[7];
  const float* br  = (const float*)d_in[8];
  const float* bz  = (const float*)d_in[9];
  const float* bh  = (const float*)d_in[10];
  float* out = (float*)d_out;

  const size_t bth = (size_t)Bb * Tt * Hh;
  dim3 pgrid(2048), pblk(256);

  proj_kernel<false><<<pgrid, pblk, 0, stream>>>(x, Wh, bh, (void*)out);

  if (ws_size >= bth * 2 * sizeof(float)) {
    float* wsz = (float*)d_ws;
    float* wsr = wsz + bth;
    proj_kernel<false><<<pgrid, pblk, 0, stream>>>(x, Wz, bz, (void*)wsz);
    proj_kernel<false><<<pgrid, pblk, 0, stream>>>(x, Wr, br, (void*)wsr);
    gru_scan_dot2<false><<<dim3(Bb), dim3(512), 0, stream>>>(
        (const void*)wsz, (const void*)wsr, hdc, Uz, Ur, Uh, out);
  } else if (ws_size >= bth * 2 * sizeof(__hip_bfloat16)) {
    __hip_bfloat16* wsz = (__hip_bfloat16*)d_ws;
    __hip_bfloat16* wsr = wsz + bth;
    proj_kernel<true><<<pgrid, pblk, 0, stream>>>(x, Wz, bz, (void*)wsz);
    proj_kernel<true><<<pgrid, pblk, 0, stream>>>(x, Wr, br, (void*)wsr);
    gru_scan_dot2<true><<<dim3(Bb), dim3(512), 0, stream>>>(
        (const void*)wsz, (const void*)wsr, hdc, Uz, Ur, Uh, out);
  }
}